// Round 1
// baseline (185.927 us; speedup 1.0000x reference)
//
#include <hip/hip_runtime.h>
#include <math.h>

#define NN 4096
#define MTOT 9
#define CH 128

// -------- Wigner-3j / TP constants (derived from reference construction) ----
#define S3f 0.57735026918962576f   // 1/sqrt(3)
#define S2f 0.70710678118654752f   // 1/sqrt(2)
#define CUf 0.54772255750516611f   // sqrt(3/10)
#define CVf 0.31622776601683794f   // sqrt(1/10)
#define CWf 0.63245553203367587f   // 2/sqrt(10)
#define CAf 0.40824829046386302f   // 1/sqrt(6)
#define CA2f 0.81649658092772603f  // 2/sqrt(6)
// COEF1 * sqrt(3/(4pi))
#define YSf ((float)(2.04665350914 * 0.48860251190291992))

// ---------------- so3_linear as tiled fp32 GEMM ----------------
// Y[n,m,:] = X[n,m,:] @ W[l(m)]  (+ bias at m==0)  (* per-l norm if apply_norm)
#define TILE_R 32
#define BK 64

__global__ __launch_bounds__(256) void so3lin_kernel(
    const float* __restrict__ X,
    const float* __restrict__ W,
    const float* __restrict__ bias,
    float* __restrict__ Y,
    const int apply_norm)
{
  __shared__ float sW[BK][CH];      // 32 KB
  __shared__ float sA[TILE_R][BK];  // 8 KB
  const int bid = blockIdx.x;
  int l, tile0, m0, nm;
  if (bid < 128)      { l = 0; tile0 = bid;       m0 = 0; nm = 1; }
  else if (bid < 512) { l = 1; tile0 = bid - 128; m0 = 1; nm = 3; }
  else                { l = 2; tile0 = bid - 512; m0 = 4; nm = 5; }
  const int row_base = tile0 * TILE_R;
  const float* Wl = W + l * CH * CH;
  const int t = threadIdx.x;
  const int tr4 = (t >> 5) * 4;   // 8 row-groups of 4
  const int tc4 = (t & 31) * 4;   // 32 col-groups of 4
  float acc[4][4] = {};

  for (int kk = 0; kk < CH; kk += BK) {
    // stage W rows kk..kk+BK-1 (BK*CH floats = 2048 float4, 8/thread)
    {
      const float4* src = (const float4*)(Wl + kk * CH);
      float4* dst = (float4*)(&sW[0][0]);
      #pragma unroll
      for (int i = 0; i < (BK * CH / 4) / 256; ++i)
        dst[t + i * 256] = src[t + i * 256];
    }
    // stage A tile: 32 rows x BK cols (512 float4, 2/thread)
    {
      #pragma unroll
      for (int i = 0; i < (TILE_R * BK / 4) / 256; ++i) {
        int ii = t + i * 256;
        int r  = ii / (BK / 4);
        int cc = (ii - r * (BK / 4)) * 4;
        int rg = row_base + r;
        int node = rg / nm;
        int m = m0 + (rg - node * nm);
        *(float4*)(&sA[r][cc]) =
            *(const float4*)(X + ((size_t)node * MTOT + m) * CH + kk + cc);
      }
    }
    __syncthreads();
    #pragma unroll 4
    for (int c = 0; c < BK; c += 4) {
      float4 b0 = *(const float4*)(&sW[c + 0][tc4]);
      float4 b1 = *(const float4*)(&sW[c + 1][tc4]);
      float4 b2 = *(const float4*)(&sW[c + 2][tc4]);
      float4 b3 = *(const float4*)(&sW[c + 3][tc4]);
      #pragma unroll
      for (int i = 0; i < 4; ++i) {
        float4 av = *(const float4*)(&sA[tr4 + i][c]);
        acc[i][0] += av.x * b0.x + av.y * b1.x + av.z * b2.x + av.w * b3.x;
        acc[i][1] += av.x * b0.y + av.y * b1.y + av.z * b2.y + av.w * b3.y;
        acc[i][2] += av.x * b0.z + av.y * b1.z + av.z * b2.z + av.w * b3.z;
        acc[i][3] += av.x * b0.w + av.y * b1.w + av.z * b2.w + av.w * b3.w;
      }
    }
    __syncthreads();
  }

  const float scale = apply_norm ? (l == 0 ? 1.0f : (l == 1 ? S3f : S2f)) : 1.0f;
  #pragma unroll
  for (int i = 0; i < 4; ++i) {
    int rg = row_base + tr4 + i;
    int node = rg / nm;
    int m = m0 + (rg - node * nm);
    float4 v;
    v.x = acc[i][0]; v.y = acc[i][1]; v.z = acc[i][2]; v.w = acc[i][3];
    if (l == 0) {   // m==0 rows only exist in l==0
      v.x += bias[tc4 + 0]; v.y += bias[tc4 + 1];
      v.z += bias[tc4 + 2]; v.w += bias[tc4 + 3];
    }
    v.x *= scale; v.y *= scale; v.z *= scale; v.w *= scale;
    *(float4*)(Y + ((size_t)node * MTOT + m) * CH + tc4) = v;
  }
}

// ---------------- gather + 4-way aggregate + fused TP (c1 - c2agg) ----------
// block: 256 threads = 2 targets x 128 channels
__global__ __launch_bounds__(256) void agg_tp_kernel(
    const float* __restrict__ X,        // exp_h1 [NN,9,128]
    const float* __restrict__ pos,      // [NN,3]
    const float* __restrict__ exp_pos,  // [NN,3]
    const float* __restrict__ alpha,    // [NN,16,8]
    const int*   __restrict__ idx,      // [NN,16]
    const float* __restrict__ tpw,      // [6,128]
    float* __restrict__ D)              // diff out [NN,9,128]
{
  __shared__ int   sIdx[2][16];
  __shared__ float sAl[2][16][8];
  __shared__ float sEy[2][16][3];
  __shared__ float sY[2][3];
  const int t  = threadIdx.x;
  const int tg = t >> 7;
  const int c  = t & 127;
  const int b  = blockIdx.x * 2 + tg;

  if (c < 16) sIdx[tg][c] = idx[b * 16 + c];
  sAl[tg][c >> 3][c & 7] = alpha[b * 128 + c];
  if (c < 3) sY[tg][c] = YSf * pos[b * 3 + c];
  __syncthreads();
  if (c < 48) {
    int j = c / 3, comp = c - 3 * j;
    sEy[tg][j][comp] = YSf * exp_pos[sIdx[tg][j] * 3 + comp];
  }
  __syncthreads();

  const int h = c >> 4;
  float a0[9] = {}, a1[9] = {}, a2[9] = {}, a3[9] = {};
  for (int j = 0; j < 16; ++j) {
    float al = sAl[tg][j][h];
    float e0 = al * sEy[tg][j][0];
    float e1 = al * sEy[tg][j][1];
    float e2 = al * sEy[tg][j][2];
    const float* xp = X + (size_t)sIdx[tg][j] * (MTOT * CH) + c;
    #pragma unroll
    for (int m = 0; m < 9; ++m) {
      float x = xp[m * CH];
      a0[m] += al * x; a1[m] += e0 * x; a2[m] += e1 * x; a3[m] += e2 * x;
    }
  }

  const float w0 = tpw[0 * CH + c], w1 = tpw[1 * CH + c], w2 = tpw[2 * CH + c];
  const float w3 = tpw[3 * CH + c], w4 = tpw[4 * CH + c], w5 = tpw[5 * CH + c];
  const float y0 = sY[tg][0], yv1 = sY[tg][1], y2 = sY[tg][2];
  const float x0 = a0[0];
  const float p0 = a0[1], p1 = a0[2], p2 = a0[3];
  const float d0 = a0[4], d1 = a0[5], d2 = a0[6], d3 = a0[7], d4 = a0[8];

  // c1 = TP(y1) . A0
  float r0 = w1 * S3f * (p0 * y0 + p1 * yv1 + p2 * y2);
  float r1 = w0 * x0 * y0 + w2 * S2f * (p1 * y2 - p2 * yv1)
           + w4 * (CUf * (d0 * y2 + d1 * yv1 - d4 * y0) - CVf * d2 * y0);
  float r2 = w0 * x0 * yv1 + w2 * S2f * (p2 * y0 - p0 * y2)
           + w4 * (CUf * (d1 * y0 + d3 * y2) + CWf * d2 * yv1);
  float r3 = w0 * x0 * y2 + w2 * S2f * (p0 * yv1 - p1 * y0)
           + w4 * (CUf * (d0 * y0 + d4 * y2 + d3 * yv1) - CVf * d2 * y2);
  float r4 = w3 * S2f * (p0 * y2 + p2 * y0)
           + w5 * (CAf * (d3 * y2 - d1 * y0) - 2.f * CAf * d4 * yv1);
  float r5 = w3 * S2f * (p0 * yv1 + p1 * y0)
           + w5 * (CAf * (d0 * y0 - d3 * yv1 + d4 * y2) + S2f * d2 * y2);
  float r6 = w3 * (CA2f * p1 * yv1 - CAf * (p0 * y0 + p2 * y2))
           + w5 * S2f * (d3 * y0 - d1 * y2);
  float r7 = w3 * S2f * (p1 * y2 + p2 * yv1)
           + w5 * (CAf * (d1 * yv1 - d0 * y2 + d4 * y0) - S2f * d2 * y0);
  float r8 = w3 * S2f * (p2 * y2 - p0 * y0)
           + w5 * CAf * (2.f * d0 * yv1 - d1 * y2 - d3 * y0);

  // c2agg = sum_b T_b . A_{b}  (replace each x[m]*y_b product with a{b+1}[m])
  float q0 = w1 * S3f * (a1[1] + a2[2] + a3[3]);
  float q1 = w0 * a1[0] + w2 * S2f * (a3[2] - a2[3])
           + w4 * (CUf * (a3[4] + a2[5] - a1[8]) - CVf * a1[6]);
  float q2 = w0 * a2[0] + w2 * S2f * (a1[3] - a3[1])
           + w4 * (CUf * (a1[5] + a3[7]) + CWf * a2[6]);
  float q3 = w0 * a3[0] + w2 * S2f * (a2[1] - a1[2])
           + w4 * (CUf * (a1[4] + a3[8] + a2[7]) - CVf * a3[6]);
  float q4 = w3 * S2f * (a3[1] + a1[3])
           + w5 * (CAf * (a3[7] - a1[5]) - 2.f * CAf * a2[8]);
  float q5 = w3 * S2f * (a2[1] + a1[2])
           + w5 * (CAf * (a1[4] - a2[7] + a3[8]) + S2f * a3[6]);
  float q6 = w3 * (CA2f * a2[2] - CAf * (a1[1] + a3[3]))
           + w5 * S2f * (a1[7] - a3[5]);
  float q7 = w3 * S2f * (a3[2] + a2[3])
           + w5 * (CAf * (a2[5] - a3[4] + a1[8]) - S2f * a1[6]);
  float q8 = w3 * S2f * (a3[3] - a1[1])
           + w5 * CAf * (2.f * a2[4] - a3[5] - a1[7]);

  float* dp = D + (size_t)b * (MTOT * CH) + c;
  dp[0 * CH] = r0 - q0;
  dp[1 * CH] = r1 - q1;
  dp[2 * CH] = r2 - q2;
  dp[3 * CH] = r3 - q3;
  dp[4 * CH] = r4 - q4;
  dp[5 * CH] = r5 - q5;
  dp[6 * CH] = r6 - q6;
  dp[7 * CH] = r7 - q7;
  dp[8 * CH] = r8 - q8;
}

extern "C" void kernel_launch(void* const* d_in, const int* in_sizes, int n_in,
                              void* d_out, int out_size, void* d_ws, size_t ws_size,
                              hipStream_t stream) {
  (void)in_sizes; (void)n_in; (void)out_size; (void)ws_size;
  const float* pos     = (const float*)d_in[0];
  const float* exp_pos = (const float*)d_in[1];
  // d_in[2] = h : unused by the reference computation
  const float* exp_h   = (const float*)d_in[3];
  const float* alpha   = (const float*)d_in[4];
  const int*   idx     = (const int*)d_in[5];
  const float* w1w     = (const float*)d_in[6];
  const float* w1b     = (const float*)d_in[7];
  const float* w2w     = (const float*)d_in[8];
  const float* w2b     = (const float*)d_in[9];
  const float* tpw     = (const float*)d_in[10];
  float* out = (float*)d_out;

  float* eh1 = (float*)d_ws;                       // [4096*9*128] fp32
  float* dif = eh1 + (size_t)NN * MTOT * CH;       // [4096*9*128] fp32

  // total row-tiles: l0 128 + l1 384 + l2 640 = 1152
  so3lin_kernel<<<1152, 256, 0, stream>>>(exp_h, w1w, w1b, eh1, 0);
  agg_tp_kernel<<<NN / 2, 256, 0, stream>>>(eh1, pos, exp_pos, alpha, idx, tpw, dif);
  so3lin_kernel<<<1152, 256, 0, stream>>>(dif, w2w, w2b, out, 1);
}

// Round 2
// 144.702 us; speedup vs baseline: 1.2849x; 1.2849x over previous
//
#include <hip/hip_runtime.h>

#define NN 4096
#define MTOT 9
#define CH 128

// -------- Wigner-3j / TP constants (verified correct in R1, fp32 pass) ----
#define S3f 0.57735026918962576f   // 1/sqrt(3)
#define S2f 0.70710678118654752f   // 1/sqrt(2)
#define CUf 0.54772255750516611f   // sqrt(3/10)
#define CVf 0.31622776601683794f   // sqrt(1/10)
#define CWf 0.63245553203367587f   // 2/sqrt(10)
#define CAf 0.40824829046386302f   // 1/sqrt(6)
#define CA2f 0.81649658092772603f  // 2/sqrt(6)
#define YSf ((float)(2.04665350914 * 0.48860251190291992))

typedef __attribute__((ext_vector_type(8))) short short8;
typedef __attribute__((ext_vector_type(4))) float f32x4;

__device__ __forceinline__ unsigned short f2b(float f) {
  unsigned u = __builtin_bit_cast(unsigned, f);
  u += 0x7FFFu + ((u >> 16) & 1u);           // RNE
  return (unsigned short)(u >> 16);
}

// ---------------- so3_linear via MFMA 16x16x32 bf16 ----------------
// Y[n,m,:] = X[n,m,:] @ W[l(m)] (+bias for l0) (*per-l norm if NORM)
// Grid: 576 blocks. l0: 0..63, l1: 64..255, l2: 256..575. 4 waves/block,
// each wave computes a 16-row x 128-col tile. W_l staged to LDS as bf16 in
// fragment order: Bs[((ct*16+kq)*16+c16)*8 + j] = W[kq*8+j][ct*16+c16]
// so a b-frag is ONE contiguous conflict-free ds_read_b128, and a wave's
// 64 lanes read a contiguous 1 KB span.
template <int XBF, int YBF, int NORM>
__global__ __launch_bounds__(256) void so3lin_mfma(
    const void* __restrict__ Xv, const float* __restrict__ W,
    const float* __restrict__ bias, void* __restrict__ Yv)
{
  __shared__ unsigned short Bs[16384];   // 32 KB swizzled bf16 W_l
  const int bid = blockIdx.x;
  int l, blk0, m0, nm;
  if (bid < 64)       { l = 0; blk0 = bid;       m0 = 0; nm = 1; }
  else if (bid < 256) { l = 1; blk0 = bid - 64;  m0 = 1; nm = 3; }
  else                { l = 2; blk0 = bid - 256; m0 = 4; nm = 5; }
  const float* Wl = W + l * CH * CH;
  const int t = threadIdx.x;

  // stage + convert W_l (64 KB fp32 -> 32 KB bf16, frag-order swizzle)
  #pragma unroll
  for (int i = 0; i < 16; ++i) {
    int idx4 = i * 256 + t;                  // float4 index, 4096 total
    float4 v = ((const float4*)Wl)[idx4];
    int k = idx4 >> 5;                       // row of W (k dim)
    int n = (idx4 & 31) * 4;                 // col of W (n dim), n%4==0
    int base = (((n >> 4) * 16 + (k >> 3)) * 16 + (n & 15)) * 8 + (k & 7);
    Bs[base]      = f2b(v.x);                // n&15 in {0,4,8,12}: +1..+3 stay in tile
    Bs[base + 8]  = f2b(v.y);
    Bs[base + 16] = f2b(v.z);
    Bs[base + 24] = f2b(v.w);
  }
  __syncthreads();

  const int lane = t & 63;
  const int wave = t >> 6;
  const int c16  = lane & 15;
  const int quad = lane >> 4;
  const int rb   = (blk0 * 4 + wave) * 16;   // tile row base (within l segment)

  // A-fragment row for this lane
  const int ra = rb + c16;
  const int nodeA = ra / nm;
  const int mA = m0 + (ra - nodeA * nm);
  const size_t abase = ((size_t)nodeA * MTOT + mA) * CH + quad * 8;

  f32x4 acc[8] = {};
  #pragma unroll
  for (int kk = 0; kk < CH; kk += 32) {
    short8 afrag;
    if (XBF) {
      afrag = *(const short8*)((const unsigned short*)Xv + abase + kk);
    } else {
      const float* xp = (const float*)Xv + abase + kk;
      float4 f0 = *(const float4*)xp;
      float4 f1 = *(const float4*)(xp + 4);
      afrag = (short8){(short)f2b(f0.x), (short)f2b(f0.y), (short)f2b(f0.z), (short)f2b(f0.w),
                       (short)f2b(f1.x), (short)f2b(f1.y), (short)f2b(f1.z), (short)f2b(f1.w)};
    }
    const int kq = (kk >> 3) + quad;
    #pragma unroll
    for (int ct = 0; ct < 8; ++ct) {
      short8 bfrag = *(const short8*)&Bs[((ct * 16 + kq) * 16 + c16) * 8];
      acc[ct] = __builtin_amdgcn_mfma_f32_16x16x32_bf16(afrag, bfrag, acc[ct], 0, 0, 0);
    }
  }

  // epilogue: C/D layout col=lane&15, row=quad*4+reg
  const float scale = NORM ? (l == 0 ? 1.0f : (l == 1 ? S3f : S2f)) : 1.0f;
  #pragma unroll
  for (int i = 0; i < 4; ++i) {
    int r2 = rb + quad * 4 + i;
    int node2 = r2 / nm;
    int m2 = m0 + (r2 - node2 * nm);
    size_t obase = ((size_t)node2 * MTOT + m2) * CH + c16;
    #pragma unroll
    for (int ct = 0; ct < 8; ++ct) {
      float v = acc[ct][i];
      if (l == 0) v += bias[ct * 16 + c16];
      v *= scale;
      if (YBF) ((unsigned short*)Yv)[obase + ct * 16] = f2b(v);
      else     ((float*)Yv)[obase + ct * 16] = v;
    }
  }
}

// ---------------- gather + 4-way aggregate + fused TP, bf16 in/out ---------
// block = 256 threads = 4 waves = 4 target nodes; lane handles 2 channels
__global__ __launch_bounds__(256) void agg_tp_b(
    const unsigned short* __restrict__ X,   // eh1 bf16 [NN,9,128]
    const float* __restrict__ pos,
    const float* __restrict__ exp_pos,
    const float* __restrict__ alpha,
    const int*   __restrict__ idx,
    const float* __restrict__ tpw,
    unsigned short* __restrict__ D)         // diff bf16 [NN,9,128]
{
  __shared__ int   sIdx[4][16];
  __shared__ float sAl[4][128];
  __shared__ float sEy[4][48];
  __shared__ float sY[4][4];
  const int t = threadIdx.x, wave = t >> 6, lane = t & 63;
  const int b = blockIdx.x * 4 + wave;

  if (lane < 16) sIdx[wave][lane] = idx[b * 16 + lane];
  sAl[wave][lane]      = alpha[b * 128 + lane];
  sAl[wave][lane + 64] = alpha[b * 128 + lane + 64];
  if (lane < 3) sY[wave][lane] = YSf * pos[b * 3 + lane];
  __syncthreads();
  if (lane < 48) {
    int j = lane / 3, cmp = lane - 3 * j;
    sEy[wave][lane] = YSf * exp_pos[sIdx[wave][j] * 3 + cmp];
  }
  __syncthreads();

  const int h = lane >> 3;       // head for both channels 2*lane, 2*lane+1
  const int c0 = lane * 2;
  float A0[9][2] = {}, A1[9][2] = {}, A2[9][2] = {}, A3[9][2] = {};
  for (int j = 0; j < 16; ++j) {
    float al = sAl[wave][j * 8 + h];
    float e0 = al * sEy[wave][j * 3 + 0];
    float e1 = al * sEy[wave][j * 3 + 1];
    float e2 = al * sEy[wave][j * 3 + 2];
    const unsigned short* xp = X + (size_t)sIdx[wave][j] * (MTOT * CH) + c0;
    #pragma unroll
    for (int m = 0; m < 9; ++m) {
      unsigned v = *(const unsigned*)(xp + m * CH);
      float x0 = __builtin_bit_cast(float, v << 16);
      float x1 = __builtin_bit_cast(float, v & 0xFFFF0000u);
      A0[m][0] += al * x0; A1[m][0] += e0 * x0; A2[m][0] += e1 * x0; A3[m][0] += e2 * x0;
      A0[m][1] += al * x1; A1[m][1] += e0 * x1; A2[m][1] += e1 * x1; A3[m][1] += e2 * x1;
    }
  }

  const float y0 = sY[wave][0], yv1 = sY[wave][1], y2 = sY[wave][2];
  float OUT[9][2];
  #pragma unroll
  for (int ch = 0; ch < 2; ++ch) {
    const int c = c0 + ch;
    const float w0 = tpw[c], w1 = tpw[CH + c], w2 = tpw[2 * CH + c];
    const float w3 = tpw[3 * CH + c], w4 = tpw[4 * CH + c], w5 = tpw[5 * CH + c];
    const float x0 = A0[0][ch];
    const float p0 = A0[1][ch], p1 = A0[2][ch], p2 = A0[3][ch];
    const float d0 = A0[4][ch], d1 = A0[5][ch], d2 = A0[6][ch], d3 = A0[7][ch], d4 = A0[8][ch];

    float r0 = w1 * S3f * (p0 * y0 + p1 * yv1 + p2 * y2);
    float r1 = w0 * x0 * y0 + w2 * S2f * (p1 * y2 - p2 * yv1)
             + w4 * (CUf * (d0 * y2 + d1 * yv1 - d4 * y0) - CVf * d2 * y0);
    float r2 = w0 * x0 * yv1 + w2 * S2f * (p2 * y0 - p0 * y2)
             + w4 * (CUf * (d1 * y0 + d3 * y2) + CWf * d2 * yv1);
    float r3 = w0 * x0 * y2 + w2 * S2f * (p0 * yv1 - p1 * y0)
             + w4 * (CUf * (d0 * y0 + d4 * y2 + d3 * yv1) - CVf * d2 * y2);
    float r4 = w3 * S2f * (p0 * y2 + p2 * y0)
             + w5 * (CAf * (d3 * y2 - d1 * y0) - 2.f * CAf * d4 * yv1);
    float r5 = w3 * S2f * (p0 * yv1 + p1 * y0)
             + w5 * (CAf * (d0 * y0 - d3 * yv1 + d4 * y2) + S2f * d2 * y2);
    float r6 = w3 * (CA2f * p1 * yv1 - CAf * (p0 * y0 + p2 * y2))
             + w5 * S2f * (d3 * y0 - d1 * y2);
    float r7 = w3 * S2f * (p1 * y2 + p2 * yv1)
             + w5 * (CAf * (d1 * yv1 - d0 * y2 + d4 * y0) - S2f * d2 * y0);
    float r8 = w3 * S2f * (p2 * y2 - p0 * y0)
             + w5 * CAf * (2.f * d0 * yv1 - d1 * y2 - d3 * y0);

    float q0 = w1 * S3f * (A1[1][ch] + A2[2][ch] + A3[3][ch]);
    float q1 = w0 * A1[0][ch] + w2 * S2f * (A3[2][ch] - A2[3][ch])
             + w4 * (CUf * (A3[4][ch] + A2[5][ch] - A1[8][ch]) - CVf * A1[6][ch]);
    float q2 = w0 * A2[0][ch] + w2 * S2f * (A1[3][ch] - A3[1][ch])
             + w4 * (CUf * (A1[5][ch] + A3[7][ch]) + CWf * A2[6][ch]);
    float q3 = w0 * A3[0][ch] + w2 * S2f * (A2[1][ch] - A1[2][ch])
             + w4 * (CUf * (A1[4][ch] + A3[8][ch] + A2[7][ch]) - CVf * A3[6][ch]);
    float q4 = w3 * S2f * (A3[1][ch] + A1[3][ch])
             + w5 * (CAf * (A3[7][ch] - A1[5][ch]) - 2.f * CAf * A2[8][ch]);
    float q5 = w3 * S2f * (A2[1][ch] + A1[2][ch])
             + w5 * (CAf * (A1[4][ch] - A2[7][ch] + A3[8][ch]) + S2f * A3[6][ch]);
    float q6 = w3 * (CA2f * A2[2][ch] - CAf * (A1[1][ch] + A3[3][ch]))
             + w5 * S2f * (A1[7][ch] - A3[5][ch]);
    float q7 = w3 * S2f * (A3[2][ch] + A2[3][ch])
             + w5 * (CAf * (A2[5][ch] - A3[4][ch] + A1[8][ch]) - S2f * A1[6][ch]);
    float q8 = w3 * S2f * (A3[3][ch] - A1[1][ch])
             + w5 * CAf * (2.f * A2[4][ch] - A3[5][ch] - A1[7][ch]);

    OUT[0][ch] = r0 - q0; OUT[1][ch] = r1 - q1; OUT[2][ch] = r2 - q2;
    OUT[3][ch] = r3 - q3; OUT[4][ch] = r4 - q4; OUT[5][ch] = r5 - q5;
    OUT[6][ch] = r6 - q6; OUT[7][ch] = r7 - q7; OUT[8][ch] = r8 - q8;
  }

  #pragma unroll
  for (int m = 0; m < 9; ++m) {
    unsigned dw = (unsigned)f2b(OUT[m][0]) | ((unsigned)f2b(OUT[m][1]) << 16);
    *(unsigned*)(D + ((size_t)b * MTOT + m) * CH + c0) = dw;
  }
}

extern "C" void kernel_launch(void* const* d_in, const int* in_sizes, int n_in,
                              void* d_out, int out_size, void* d_ws, size_t ws_size,
                              hipStream_t stream) {
  (void)in_sizes; (void)n_in; (void)out_size; (void)ws_size;
  const float* pos     = (const float*)d_in[0];
  const float* exp_pos = (const float*)d_in[1];
  // d_in[2] = h : unused by the reference computation
  const float* exp_h   = (const float*)d_in[3];
  const float* alpha   = (const float*)d_in[4];
  const int*   idx     = (const int*)d_in[5];
  const float* w1w     = (const float*)d_in[6];
  const float* w1b     = (const float*)d_in[7];
  const float* w2w     = (const float*)d_in[8];
  const float* w2b     = (const float*)d_in[9];
  const float* tpw     = (const float*)d_in[10];
  float* out = (float*)d_out;

  unsigned short* eh1 = (unsigned short*)d_ws;                  // bf16 [4096*9*128]
  unsigned short* dif = eh1 + (size_t)NN * MTOT * CH;           // bf16 [4096*9*128]

  so3lin_mfma<0, 1, 0><<<576, 256, 0, stream>>>(exp_h, w1w, w1b, eh1);
  agg_tp_b<<<NN / 4, 256, 0, stream>>>(eh1, pos, exp_pos, alpha, idx, tpw, dif);
  so3lin_mfma<1, 0, 1><<<576, 256, 0, stream>>>(dif, w2w, w2b, out);
}